// Round 16
// baseline (216.278 us; speedup 1.0000x reference)
//
#include <hip/hip_runtime.h>
#include <stdint.h>

#define N_NODES 10000
#define N_EDGES 320000
#define D_IN    512
#define D_HID   2048
#define N_CLS   40
#define MP2     10240   // Pb padded rows (gemm1 reads 40*256 rows)
#define HSTR    136     // Hs row stride (shorts): 272B, breaks pow2 banks

typedef float f32x4  __attribute__((ext_vector_type(4)));
typedef short bf16x8 __attribute__((ext_vector_type(8)));
typedef unsigned short us8 __attribute__((ext_vector_type(8)));

__device__ inline unsigned short f2bf(float f){
  unsigned int u = __float_as_uint(f);
  u += 0x7fffu + ((u >> 16) & 1u);   // round-to-nearest-even
  return (unsigned short)(u >> 16);
}

__device__ inline float bf2f(unsigned short h){
  return __uint_as_float(((unsigned int)h) << 16);
}

__device__ inline void gl_lds16(const void* g, void* l){
  __builtin_amdgcn_global_load_lds((const __attribute__((address_space(1))) void*)g,
                                   (__attribute__((address_space(3))) void*)l, 16, 0, 0);
}

// ---------------- fused: x->bf16 cast + degree count ----------------
__global__ void k_prep0(const float* __restrict__ x, unsigned short* __restrict__ Xb,
                        const int* __restrict__ ei, int* __restrict__ deg){
  if (blockIdx.x < 2500){
    int idx = blockIdx.x*256 + threadIdx.x;
    const f32x4* x4 = (const f32x4*)x;
    f32x4 a = x4[idx*2], b = x4[idx*2+1];
    us8 o;
    o[0]=f2bf(a.x); o[1]=f2bf(a.y); o[2]=f2bf(a.z); o[3]=f2bf(a.w);
    o[4]=f2bf(b.x); o[5]=f2bf(b.y); o[6]=f2bf(b.z); o[7]=f2bf(b.w);
    *(us8*)(Xb + (size_t)idx*8) = o;
  } else {
    int e = (blockIdx.x - 2500)*256 + threadIdx.x;
    if (e < N_EDGES) atomicAdd(&deg[ei[N_EDGES + e]], 1);
  }
}

// exclusive scan of deg -> cursor (LDS-staged, coalesced), + dinv
__global__ void k_scan(const int* __restrict__ deg, int* __restrict__ cursor,
                       float* __restrict__ dinv){
  __shared__ int sdeg[N_NODES];
  __shared__ int sums[1024];
  const int t = threadIdx.x;
  for (int j = t; j < N_NODES; j += 1024){
    int v = deg[j];
    sdeg[j] = v;
    dinv[j] = rsqrtf((float)v + 1.0f);
  }
  __syncthreads();
  const int CH = 10;
  int base = t*CH;
  int local[CH]; int s = 0;
  for (int j = 0; j < CH; j++){
    int v = (base + j < N_NODES) ? sdeg[base + j] : 0;
    local[j] = s; s += v;
  }
  sums[t] = s;
  __syncthreads();
  for (int off = 1; off < 1024; off <<= 1){
    int v = (t >= off) ? sums[t - off] : 0;
    __syncthreads();
    sums[t] += v;
    __syncthreads();
  }
  int pre = (t > 0) ? sums[t-1] : 0;
  for (int j = 0; j < CH; j++){
    int idx = base + j;
    if (idx < N_NODES) sdeg[idx] = pre + local[j];
  }
  __syncthreads();
  for (int j = t; j < N_NODES; j += 1024) cursor[j] = sdeg[j];
}

__global__ void k_fill(const int* __restrict__ ei, int* __restrict__ cursor, int* __restrict__ csr_src){
  int e = blockIdx.x*256 + threadIdx.x;
  if (e < N_EDGES){
    int s = ei[e], d = ei[N_EDGES + e];
    int pos = atomicAdd(&cursor[d], 1);
    csr_src[pos] = s;
  }
}

// ---------------- fused: gather1 v4 (blocks 0..624) + weight prep ----------------
// Gather v4 (loose lockstep): one block = 16 nodes, 4 waves; wave = 4 nodes x
// 128-col slice. Block LOOPS slices 0..3 sequentially -- all 625 blocks start
// on slice 0 together and drift only by degree variance, so the live Xb
// working set is ~1-1.5 slices (2.6-3.8MB) per XCD < 4MiB L2 -> row loads hit
// L2 (~35TB/s) not L3 (~8TB/s). Per-node/slice edge order unchanged (bitwise-
// same Pb vs v3). csr chunk re-read per slice (L2-hot, negligible).
__global__ __launch_bounds__(256) void k_gjoint(const unsigned short* __restrict__ Xb,
                          const int* __restrict__ csr_src,
                          const int* __restrict__ cursor, const int* __restrict__ deg,
                          const float* __restrict__ dinv, unsigned short* __restrict__ Pb,
                          const float* __restrict__ W1, unsigned short* __restrict__ Wt1,
                          const float* __restrict__ W2, unsigned short* __restrict__ Wt2){
  __shared__ float tile[32][33];
  if (blockIdx.x < 625){
    const int w    = threadIdx.x >> 6;        // wave 0..3
    const int lane = threadIdx.x & 63;
    const int g    = lane >> 4;               // node group 0..3
    const int sub  = lane & 15;               // 16 lanes per node
    const int i    = blockIdx.x*16 + w*4 + g; // this lane's node
    const float di = dinv[i];
    const float dii = di*di;
    const int cnt = deg[i];
    const int start = cursor[i] - cnt;
    // wave-uniform max degree over the wave's 4 groups (bits 4,5 of lane)
    int mc = cnt;
    mc = max(mc, __shfl_xor(mc, 16));
    mc = max(mc, __shfl_xor(mc, 32));
    const int lb = g*16;                      // group's base lane
    for (int sl = 0; sl < 4; sl++){
      const int col0 = sl*128;
      const unsigned short* Xl = Xb + col0 + sub*8;
      float acc[8];
      us8 xi = *(const us8*)(Xl + (size_t)i*D_IN);
      #pragma unroll
      for (int r = 0; r < 8; r++) acc[r] = dii * bf2f(xi[r]);
      for (int c0 = 0; c0 < mc; c0 += 16){
        int s = i; float cf = 0.0f;
        if (sub < cnt - c0){ s = csr_src[start + c0 + sub]; cf = dinv[s]*di; }
        int jm = mc - c0; if (jm > 16) jm = 16;
        int j = 0;
        for (; j + 8 <= jm; j += 8){
          int   s0 = __shfl(s, lb+j),   s1 = __shfl(s, lb+j+1), s2 = __shfl(s, lb+j+2), s3 = __shfl(s, lb+j+3);
          int   s4 = __shfl(s, lb+j+4), s5 = __shfl(s, lb+j+5), s6 = __shfl(s, lb+j+6), s7 = __shfl(s, lb+j+7);
          float c0f = __shfl(cf, lb+j),   c1f = __shfl(cf, lb+j+1), c2f = __shfl(cf, lb+j+2), c3f = __shfl(cf, lb+j+3);
          float c4f = __shfl(cf, lb+j+4), c5f = __shfl(cf, lb+j+5), c6f = __shfl(cf, lb+j+6), c7f = __shfl(cf, lb+j+7);
          us8 x0 = *(const us8*)(Xl + (size_t)s0*D_IN);
          us8 x1 = *(const us8*)(Xl + (size_t)s1*D_IN);
          us8 x2 = *(const us8*)(Xl + (size_t)s2*D_IN);
          us8 x3 = *(const us8*)(Xl + (size_t)s3*D_IN);
          us8 x4 = *(const us8*)(Xl + (size_t)s4*D_IN);
          us8 x5 = *(const us8*)(Xl + (size_t)s5*D_IN);
          us8 x6 = *(const us8*)(Xl + (size_t)s6*D_IN);
          us8 x7 = *(const us8*)(Xl + (size_t)s7*D_IN);
          #pragma unroll
          for (int r = 0; r < 8; r++) acc[r] += c0f * bf2f(x0[r]);
          #pragma unroll
          for (int r = 0; r < 8; r++) acc[r] += c1f * bf2f(x1[r]);
          #pragma unroll
          for (int r = 0; r < 8; r++) acc[r] += c2f * bf2f(x2[r]);
          #pragma unroll
          for (int r = 0; r < 8; r++) acc[r] += c3f * bf2f(x3[r]);
          #pragma unroll
          for (int r = 0; r < 8; r++) acc[r] += c4f * bf2f(x4[r]);
          #pragma unroll
          for (int r = 0; r < 8; r++) acc[r] += c5f * bf2f(x5[r]);
          #pragma unroll
          for (int r = 0; r < 8; r++) acc[r] += c6f * bf2f(x6[r]);
          #pragma unroll
          for (int r = 0; r < 8; r++) acc[r] += c7f * bf2f(x7[r]);
        }
        for (; j < jm; j++){
          int   sj = __shfl(s, lb+j);
          float cj = __shfl(cf, lb+j);
          us8 xr = *(const us8*)(Xl + (size_t)sj*D_IN);
          #pragma unroll
          for (int r = 0; r < 8; r++) acc[r] += cj * bf2f(xr[r]);
        }
      }
      us8 o;
      #pragma unroll
      for (int r = 0; r < 8; r++) o[r] = f2bf(acc[r]);
      *(us8*)(Pb + (size_t)i*D_IN + col0 + sub*8) = o;
    }
  } else if (blockIdx.x < 625 + 1024){
    const int bb = blockIdx.x - 625;
    const int n0 = (bb & 63)*32, k0 = (bb >> 6)*32;
    const int tx = threadIdx.x & 31, ty = threadIdx.x >> 5;
    for (int i = 0; i < 32; i += 8)
      tile[ty+i][tx] = W1[(size_t)(k0+ty+i)*D_HID + n0+tx];
    __syncthreads();
    for (int i = 0; i < 32; i += 8)
      Wt1[(size_t)(n0+ty+i)*D_IN + k0+tx] = f2bf(tile[tx][ty+i]);
  } else {
    int idx = (blockIdx.x - 1649)*256 + threadIdx.x;
    if (idx < 48*D_HID){
      int n = idx >> 11, k = idx & (D_HID-1);
      Wt2[idx] = (n < N_CLS) ? f2bf(W2[k*N_CLS + n]) : (unsigned short)0;
    }
  }
}

// ---------------- GEMM1+GEMM2 fused v3: 256x128 tile, 512 threads ----------------
// (R14-proven: time ~ staged bytes; 242MB. dbuf vmcnt(3); Gp partials.)
__global__ __launch_bounds__(512, 4) void k_gemm1f(const unsigned short* __restrict__ Pb,
                                                   const unsigned short* __restrict__ Wt1,
                                                   const float* __restrict__ b1,
                                                   const unsigned short* __restrict__ Wt2,
                                                   float* __restrict__ Gp){
  __shared__ short smem[256*HSTR];     // 69632 B; K-loop uses first 49152 B as 2 bufs
  short* Hs = smem;
  const int t    = threadIdx.x;
  const int lane = t & 63;
  const int wid  = t >> 6;             // 0..7
  const int wm   = (wid >> 1)*64;      // 0,64,128,192
  const int wn   = (wid & 1)*64;       // 0,64
  const int m0   = blockIdx.y*256, n0 = blockIdx.x*128;
  const int arow = t >> 2;             // 0..127
  const int akof = ((t & 3) ^ ((t >> 3) & 3))*8;  // swizzled source chunk
  const int fr   = lane & 15;
  const int q    = lane >> 4;
  const int sq8  = (q ^ ((fr >> 1) & 3))*8;       // swizzled read offset

  const unsigned short* ApA = Pb  + (size_t)(m0 +       arow)*D_IN + akof;
  const unsigned short* ApB = Pb  + (size_t)(m0 + 128 + arow)*D_IN + akof;
  const unsigned short* BpA = Wt1 + (size_t)(n0 +       arow)*D_IN + akof;

  f32x4 acc[4][4] = {};
  // prologue: stage iter 0 into buf 0 (A rows 0-127, A rows 128-255, B rows 0-127)
  {
    gl_lds16(ApA, smem + t*8);
    gl_lds16(ApB, smem + 4096 + t*8);
    gl_lds16(BpA, smem + 8192 + t*8);
  }
  #pragma unroll
  for (int ks = 0; ks < 16; ks++){
    if (ks < 15){
      short* buf = smem + ((ks+1)&1)*12288;
      const int kb = (ks+1)*32;
      gl_lds16(ApA + kb, buf + t*8);
      gl_lds16(ApB + kb, buf + 4096 + t*8);
      gl_lds16(BpA + kb, buf + 8192 + t*8);
      asm volatile("" ::: "memory");
      __builtin_amdgcn_s_waitcnt(0x0F73);   // vmcnt(3): current buf done, next in flight
    } else {
      asm volatile("" ::: "memory");
      __builtin_amdgcn_s_waitcnt(0x0F70);   // vmcnt(0): last buf
    }
    __builtin_amdgcn_s_barrier();
    asm volatile("" ::: "memory");
    const short* As = smem + (ks&1)*12288;  // rows 0..255, row r at r*32 shorts
    const short* Bs = As + 8192;            // rows 0..127
    bf16x8 a[4], b[4];
    #pragma unroll
    for (int i = 0; i < 4; i++) a[i] = *(const bf16x8*)(As + (wm + i*16 + fr)*32 + sq8);
    #pragma unroll
    for (int j = 0; j < 4; j++) b[j] = *(const bf16x8*)(Bs + (wn + j*16 + fr)*32 + sq8);
    #pragma unroll
    for (int i = 0; i < 4; i++)
      #pragma unroll
      for (int j = 0; j < 4; j++)
        acc[i][j] = __builtin_amdgcn_mfma_f32_16x16x32_bf16(a[i], b[j], acc[i][j], 0, 0, 0);
    asm volatile("" ::: "memory");
    __builtin_amdgcn_s_barrier();           // reads of this buf done before overwrite
    asm volatile("" ::: "memory");
  }
  // epilogue stage A: bias+ReLU, 256x128 H tile -> LDS bf16
  #pragma unroll
  for (int j = 0; j < 4; j++){
    int col = wn + j*16 + fr;
    float bias = b1[n0 + col];
    #pragma unroll
    for (int i = 0; i < 4; i++){
      int rbase = wm + i*16 + q*4;
      f32x4 v = acc[i][j];
      #pragma unroll
      for (int r = 0; r < 4; r++){
        float h = fmaxf(v[r] + bias, 0.0f);
        Hs[(rbase + r)*HSTR + col] = (short)f2bf(h);
      }
    }
  }
  __syncthreads();
  // epilogue stage B: Gp[panel] partial = Hs @ Wt2[:, n0:n0+128]^T ; wave owns 32 rows
  f32x4 acc2[2][3] = {};
  for (int ks = 0; ks < 4; ks++){
    bf16x8 a2[2];
    #pragma unroll
    for (int i2 = 0; i2 < 2; i2++)
      a2[i2] = *(const bf16x8*)(Hs + (wid*32 + i2*16 + fr)*HSTR + ks*32 + q*8);
    #pragma unroll
    for (int j2 = 0; j2 < 3; j2++){
      bf16x8 b2 = *(const bf16x8*)(Wt2 + (size_t)(j2*16 + fr)*D_HID + n0 + ks*32 + q*8);
      #pragma unroll
      for (int i2 = 0; i2 < 2; i2++)
        acc2[i2][j2] = __builtin_amdgcn_mfma_f32_16x16x32_bf16(a2[i2], b2, acc2[i2][j2], 0, 0, 0);
    }
  }
  float* Gpp = Gp + (size_t)blockIdx.x*N_NODES*N_CLS;
  #pragma unroll
  for (int j2 = 0; j2 < 3; j2++){
    int col = j2*16 + fr;
    if (col < N_CLS){
      #pragma unroll
      for (int i2 = 0; i2 < 2; i2++){
        int rbase = m0 + wid*32 + i2*16 + q*4;
        f32x4 v = acc2[i2][j2];
        #pragma unroll
        for (int r = 0; r < 4; r++){
          int row = rbase + r;
          if (row < N_NODES)
            Gpp[(size_t)row*N_CLS + col] = v[r];   // plain store, no contention
        }
      }
    }
  }
}

// ---------------- reduce 16 panel partials -> G ----------------
__global__ void k_reduceG(const float* __restrict__ Gp, float* __restrict__ G){
  int idx = blockIdx.x*256 + threadIdx.x;
  if (idx < N_NODES*N_CLS){
    float s = 0.0f;
    #pragma unroll
    for (int p = 0; p < 16; p++)
      s += Gp[(size_t)p*N_NODES*N_CLS + idx];
    G[idx] = s;
  }
}

// ---------------- propagate(G) + b2 -> out ----------------
__global__ void k_gather2(const float* __restrict__ G, const int* __restrict__ csr_src,
                          const int* __restrict__ cursor, const int* __restrict__ deg,
                          const float* __restrict__ dinv, const float* __restrict__ b2,
                          float* __restrict__ out){
  __shared__ int   ssrc[64];
  __shared__ float scoef[64];
  const int i = blockIdx.x;
  const int t = threadIdx.x;
  const float di = dinv[i];
  const int cnt = deg[i];
  const int start = cursor[i] - cnt;
  float acc = 0.0f;
  if (t < N_CLS) acc = di*di * G[i*N_CLS + t];
  for (int c0 = 0; c0 < cnt; c0 += 64){
    int m = cnt - c0; if (m > 64) m = 64;
    if (t < m){
      int s = csr_src[start + c0 + t];
      ssrc[t] = s; scoef[t] = dinv[s]*di;
    }
    __syncthreads();
    if (t < N_CLS)
      for (int j = 0; j < m; j++)
        acc += scoef[j] * G[ssrc[j]*N_CLS + t];
    __syncthreads();
  }
  if (t < N_CLS) out[i*N_CLS + t] = acc + b2[t];
}

extern "C" void kernel_launch(void* const* d_in, const int* in_sizes, int n_in,
                              void* d_out, int out_size, void* d_ws, size_t ws_size,
                              hipStream_t stream){
  const float* x  = (const float*)d_in[0];
  const int*   ei = (const int*)d_in[1];
  const float* W1 = (const float*)d_in[2];
  const float* b1 = (const float*)d_in[3];
  const float* W2 = (const float*)d_in[4];
  const float* b2 = (const float*)d_in[5];
  float* out = (float*)d_out;

  char* ws = (char*)d_ws;
  size_t off = 0;
  auto alloc = [&](size_t bytes) -> void* {
    void* p = ws + off; off += (bytes + 255) & ~(size_t)255; return p;
  };
  int*   deg     = (int*)alloc((size_t)N_NODES*4);
  float* dinv    = (float*)alloc((size_t)N_NODES*4);
  int*   cursor  = (int*)alloc((size_t)N_NODES*4);
  int*   csr     = (int*)alloc((size_t)N_EDGES*4);
  unsigned short* Xb  = (unsigned short*)alloc((size_t)N_NODES*D_IN*2);
  unsigned short* Pb  = (unsigned short*)alloc((size_t)MP2*D_IN*2);
  unsigned short* Wt1 = (unsigned short*)alloc((size_t)D_HID*D_IN*2);
  unsigned short* Wt2 = (unsigned short*)alloc((size_t)48*D_HID*2);
  float* G  = (float*)alloc((size_t)N_NODES*N_CLS*4);
  float* Gp = (float*)alloc((size_t)16*N_NODES*N_CLS*4);   // 25.6 MB partials

  hipMemsetAsync(deg, 0, (size_t)N_NODES*4, stream);

  k_prep0<<<2500 + 1250, 256, 0, stream>>>(x, Xb, ei, deg);
  k_scan<<<1, 1024, 0, stream>>>(deg, cursor, dinv);
  k_fill<<<(N_EDGES+255)/256, 256, 0, stream>>>(ei, cursor, csr);
  k_gjoint<<<625 + 1024 + 384, 256, 0, stream>>>(Xb, csr, cursor, deg, dinv, Pb,
                                                 W1, Wt1, W2, Wt2);
  k_gemm1f<<<dim3(D_HID/128, MP2/256), 512, 0, stream>>>(Pb, Wt1, b1, Wt2, Gp);
  k_reduceG<<<(N_NODES*N_CLS + 255)/256, 256, 0, stream>>>(Gp, G);
  k_gather2<<<N_NODES, 64, 0, stream>>>(G, csr, cursor, deg, dinv, b2, out);
}

// Round 17
// 204.715 us; speedup vs baseline: 1.0565x; 1.0565x over previous
//
#include <hip/hip_runtime.h>
#include <stdint.h>

#define N_NODES 10000
#define N_EDGES 320000
#define D_IN    512
#define D_HID   2048
#define N_CLS   40
#define MP2     10240   // Pb padded rows (gemm1 reads 40*256 rows)
#define HSTR    136     // Hs row stride (shorts): 272B, breaks pow2 banks
#define NGB     2504    // gather blocks: 8*313, slice=(b>>1)&3 pins slice to XCD pair

typedef float f32x4  __attribute__((ext_vector_type(4)));
typedef short bf16x8 __attribute__((ext_vector_type(8)));
typedef unsigned short us8 __attribute__((ext_vector_type(8)));

__device__ inline unsigned short f2bf(float f){
  unsigned int u = __float_as_uint(f);
  u += 0x7fffu + ((u >> 16) & 1u);   // round-to-nearest-even
  return (unsigned short)(u >> 16);
}

__device__ inline float bf2f(unsigned short h){
  return __uint_as_float(((unsigned int)h) << 16);
}

__device__ inline void gl_lds16(const void* g, void* l){
  __builtin_amdgcn_global_load_lds((const __attribute__((address_space(1))) void*)g,
                                   (__attribute__((address_space(3))) void*)l, 16, 0, 0);
}

// ---------------- fused: x->bf16 cast + degree count ----------------
__global__ void k_prep0(const float* __restrict__ x, unsigned short* __restrict__ Xb,
                        const int* __restrict__ ei, int* __restrict__ deg){
  if (blockIdx.x < 2500){
    int idx = blockIdx.x*256 + threadIdx.x;
    const f32x4* x4 = (const f32x4*)x;
    f32x4 a = x4[idx*2], b = x4[idx*2+1];
    us8 o;
    o[0]=f2bf(a.x); o[1]=f2bf(a.y); o[2]=f2bf(a.z); o[3]=f2bf(a.w);
    o[4]=f2bf(b.x); o[5]=f2bf(b.y); o[6]=f2bf(b.z); o[7]=f2bf(b.w);
    *(us8*)(Xb + (size_t)idx*8) = o;
  } else {
    int e = (blockIdx.x - 2500)*256 + threadIdx.x;
    if (e < N_EDGES) atomicAdd(&deg[ei[N_EDGES + e]], 1);
  }
}

// exclusive scan of deg -> cursor (LDS-staged, coalesced), + dinv
__global__ void k_scan(const int* __restrict__ deg, int* __restrict__ cursor,
                       float* __restrict__ dinv){
  __shared__ int sdeg[N_NODES];
  __shared__ int sums[1024];
  const int t = threadIdx.x;
  for (int j = t; j < N_NODES; j += 1024){
    int v = deg[j];
    sdeg[j] = v;
    dinv[j] = rsqrtf((float)v + 1.0f);
  }
  __syncthreads();
  const int CH = 10;
  int base = t*CH;
  int local[CH]; int s = 0;
  for (int j = 0; j < CH; j++){
    int v = (base + j < N_NODES) ? sdeg[base + j] : 0;
    local[j] = s; s += v;
  }
  sums[t] = s;
  __syncthreads();
  for (int off = 1; off < 1024; off <<= 1){
    int v = (t >= off) ? sums[t - off] : 0;
    __syncthreads();
    sums[t] += v;
    __syncthreads();
  }
  int pre = (t > 0) ? sums[t-1] : 0;
  for (int j = 0; j < CH; j++){
    int idx = base + j;
    if (idx < N_NODES) sdeg[idx] = pre + local[j];
  }
  __syncthreads();
  for (int j = t; j < N_NODES; j += 1024) cursor[j] = sdeg[j];
}

__global__ void k_fill(const int* __restrict__ ei, int* __restrict__ cursor, int* __restrict__ csr_src){
  int e = blockIdx.x*256 + threadIdx.x;
  if (e < N_EDGES){
    int s = ei[e], d = ei[N_EDGES + e];
    int pos = atomicAdd(&cursor[d], 1);
    csr_src[pos] = s;
  }
}

// ---------------- fused: gather1 v5 (blocks 0..NGB-1) + weight prep ----------------
// Gather v5 (XCD-pinned slices): wave = 4 nodes x 128-col slice (v3 layout,
// 10016 waves for latency hiding). slice = (b>>1)&3 so linear-dispatch
// round-robin (block b -> XCD b%8) puts slice s only on XCDs {2s,2s+1}:
// per-XCD live Xb working set = one 2.56MB slice < 4MiB L2, permanently.
// k = (b>>3)*2+(b&1) in [0,626), guard k<625. Edge order per (node,slice)
// unchanged (16-chunks, csr order) -> bitwise-same Pb vs R15/R16.
__global__ __launch_bounds__(256) void k_gjoint(const unsigned short* __restrict__ Xb,
                          const int* __restrict__ csr_src,
                          const int* __restrict__ cursor, const int* __restrict__ deg,
                          const float* __restrict__ dinv, unsigned short* __restrict__ Pb,
                          const float* __restrict__ W1, unsigned short* __restrict__ Wt1,
                          const float* __restrict__ W2, unsigned short* __restrict__ Wt2){
  __shared__ float tile[32][33];
  if (blockIdx.x < NGB){
    const int b  = blockIdx.x;
    const int sl = (b >> 1) & 3;              // slice, pinned to XCD pair
    const int k  = (b >> 3)*2 + (b & 1);      // node-group 0..625
    if (k >= 625) return;
    const int w    = threadIdx.x >> 6;        // wave 0..3
    const int lane = threadIdx.x & 63;
    const int g    = lane >> 4;               // node group 0..3
    const int sub  = lane & 15;               // 16 lanes per node
    const int i    = k*16 + w*4 + g;          // this lane's node
    const int col0 = sl*128;
    const float di = dinv[i];
    const float dii = di*di;
    const int cnt = deg[i];
    const int start = cursor[i] - cnt;
    int mc = cnt;
    mc = max(mc, __shfl_xor(mc, 16));
    mc = max(mc, __shfl_xor(mc, 32));
    const int lb = g*16;                      // group's base lane
    const unsigned short* Xl = Xb + col0 + sub*8;
    float acc[8];
    us8 xi = *(const us8*)(Xl + (size_t)i*D_IN);
    #pragma unroll
    for (int r = 0; r < 8; r++) acc[r] = dii * bf2f(xi[r]);
    for (int c0 = 0; c0 < mc; c0 += 16){
      int s = i; float cf = 0.0f;
      if (sub < cnt - c0){ s = csr_src[start + c0 + sub]; cf = dinv[s]*di; }
      int jm = mc - c0; if (jm > 16) jm = 16;
      int j = 0;
      for (; j + 8 <= jm; j += 8){
        int   s0 = __shfl(s, lb+j),   s1 = __shfl(s, lb+j+1), s2 = __shfl(s, lb+j+2), s3 = __shfl(s, lb+j+3);
        int   s4 = __shfl(s, lb+j+4), s5 = __shfl(s, lb+j+5), s6 = __shfl(s, lb+j+6), s7 = __shfl(s, lb+j+7);
        float c0f = __shfl(cf, lb+j),   c1f = __shfl(cf, lb+j+1), c2f = __shfl(cf, lb+j+2), c3f = __shfl(cf, lb+j+3);
        float c4f = __shfl(cf, lb+j+4), c5f = __shfl(cf, lb+j+5), c6f = __shfl(cf, lb+j+6), c7f = __shfl(cf, lb+j+7);
        us8 x0 = *(const us8*)(Xl + (size_t)s0*D_IN);
        us8 x1 = *(const us8*)(Xl + (size_t)s1*D_IN);
        us8 x2 = *(const us8*)(Xl + (size_t)s2*D_IN);
        us8 x3 = *(const us8*)(Xl + (size_t)s3*D_IN);
        us8 x4 = *(const us8*)(Xl + (size_t)s4*D_IN);
        us8 x5 = *(const us8*)(Xl + (size_t)s5*D_IN);
        us8 x6 = *(const us8*)(Xl + (size_t)s6*D_IN);
        us8 x7 = *(const us8*)(Xl + (size_t)s7*D_IN);
        #pragma unroll
        for (int r = 0; r < 8; r++) acc[r] += c0f * bf2f(x0[r]);
        #pragma unroll
        for (int r = 0; r < 8; r++) acc[r] += c1f * bf2f(x1[r]);
        #pragma unroll
        for (int r = 0; r < 8; r++) acc[r] += c2f * bf2f(x2[r]);
        #pragma unroll
        for (int r = 0; r < 8; r++) acc[r] += c3f * bf2f(x3[r]);
        #pragma unroll
        for (int r = 0; r < 8; r++) acc[r] += c4f * bf2f(x4[r]);
        #pragma unroll
        for (int r = 0; r < 8; r++) acc[r] += c5f * bf2f(x5[r]);
        #pragma unroll
        for (int r = 0; r < 8; r++) acc[r] += c6f * bf2f(x6[r]);
        #pragma unroll
        for (int r = 0; r < 8; r++) acc[r] += c7f * bf2f(x7[r]);
      }
      for (; j < jm; j++){
        int   sj = __shfl(s, lb+j);
        float cj = __shfl(cf, lb+j);
        us8 xr = *(const us8*)(Xl + (size_t)sj*D_IN);
        #pragma unroll
        for (int r = 0; r < 8; r++) acc[r] += cj * bf2f(xr[r]);
      }
    }
    us8 o;
    #pragma unroll
    for (int r = 0; r < 8; r++) o[r] = f2bf(acc[r]);
    *(us8*)(Pb + (size_t)i*D_IN + col0 + sub*8) = o;
  } else if (blockIdx.x < NGB + 1024){
    const int bb = blockIdx.x - NGB;
    const int n0 = (bb & 63)*32, k0 = (bb >> 6)*32;
    const int tx = threadIdx.x & 31, ty = threadIdx.x >> 5;
    for (int i = 0; i < 32; i += 8)
      tile[ty+i][tx] = W1[(size_t)(k0+ty+i)*D_HID + n0+tx];
    __syncthreads();
    for (int i = 0; i < 32; i += 8)
      Wt1[(size_t)(n0+ty+i)*D_IN + k0+tx] = f2bf(tile[tx][ty+i]);
  } else {
    int idx = (blockIdx.x - (NGB + 1024))*256 + threadIdx.x;
    if (idx < 48*D_HID){
      int n = idx >> 11, k = idx & (D_HID-1);
      Wt2[idx] = (n < N_CLS) ? f2bf(W2[k*N_CLS + n]) : (unsigned short)0;
    }
  }
}

// ---------------- GEMM1+GEMM2 fused v3: 256x128 tile, 512 threads ----------------
// (R14-proven: time ~ staged bytes; 242MB. dbuf vmcnt(3); Gp partials.)
__global__ __launch_bounds__(512, 4) void k_gemm1f(const unsigned short* __restrict__ Pb,
                                                   const unsigned short* __restrict__ Wt1,
                                                   const float* __restrict__ b1,
                                                   const unsigned short* __restrict__ Wt2,
                                                   float* __restrict__ Gp){
  __shared__ short smem[256*HSTR];     // 69632 B; K-loop uses first 49152 B as 2 bufs
  short* Hs = smem;
  const int t    = threadIdx.x;
  const int lane = t & 63;
  const int wid  = t >> 6;             // 0..7
  const int wm   = (wid >> 1)*64;      // 0,64,128,192
  const int wn   = (wid & 1)*64;       // 0,64
  const int m0   = blockIdx.y*256, n0 = blockIdx.x*128;
  const int arow = t >> 2;             // 0..127
  const int akof = ((t & 3) ^ ((t >> 3) & 3))*8;  // swizzled source chunk
  const int fr   = lane & 15;
  const int q    = lane >> 4;
  const int sq8  = (q ^ ((fr >> 1) & 3))*8;       // swizzled read offset

  const unsigned short* ApA = Pb  + (size_t)(m0 +       arow)*D_IN + akof;
  const unsigned short* ApB = Pb  + (size_t)(m0 + 128 + arow)*D_IN + akof;
  const unsigned short* BpA = Wt1 + (size_t)(n0 +       arow)*D_IN + akof;

  f32x4 acc[4][4] = {};
  // prologue: stage iter 0 into buf 0 (A rows 0-127, A rows 128-255, B rows 0-127)
  {
    gl_lds16(ApA, smem + t*8);
    gl_lds16(ApB, smem + 4096 + t*8);
    gl_lds16(BpA, smem + 8192 + t*8);
  }
  #pragma unroll
  for (int ks = 0; ks < 16; ks++){
    if (ks < 15){
      short* buf = smem + ((ks+1)&1)*12288;
      const int kb = (ks+1)*32;
      gl_lds16(ApA + kb, buf + t*8);
      gl_lds16(ApB + kb, buf + 4096 + t*8);
      gl_lds16(BpA + kb, buf + 8192 + t*8);
      asm volatile("" ::: "memory");
      __builtin_amdgcn_s_waitcnt(0x0F73);   // vmcnt(3): current buf done, next in flight
    } else {
      asm volatile("" ::: "memory");
      __builtin_amdgcn_s_waitcnt(0x0F70);   // vmcnt(0): last buf
    }
    __builtin_amdgcn_s_barrier();
    asm volatile("" ::: "memory");
    const short* As = smem + (ks&1)*12288;  // rows 0..255, row r at r*32 shorts
    const short* Bs = As + 8192;            // rows 0..127
    bf16x8 a[4], b[4];
    #pragma unroll
    for (int i = 0; i < 4; i++) a[i] = *(const bf16x8*)(As + (wm + i*16 + fr)*32 + sq8);
    #pragma unroll
    for (int j = 0; j < 4; j++) b[j] = *(const bf16x8*)(Bs + (wn + j*16 + fr)*32 + sq8);
    #pragma unroll
    for (int i = 0; i < 4; i++)
      #pragma unroll
      for (int j = 0; j < 4; j++)
        acc[i][j] = __builtin_amdgcn_mfma_f32_16x16x32_bf16(a[i], b[j], acc[i][j], 0, 0, 0);
    asm volatile("" ::: "memory");
    __builtin_amdgcn_s_barrier();           // reads of this buf done before overwrite
    asm volatile("" ::: "memory");
  }
  // epilogue stage A: bias+ReLU, 256x128 H tile -> LDS bf16
  #pragma unroll
  for (int j = 0; j < 4; j++){
    int col = wn + j*16 + fr;
    float bias = b1[n0 + col];
    #pragma unroll
    for (int i = 0; i < 4; i++){
      int rbase = wm + i*16 + q*4;
      f32x4 v = acc[i][j];
      #pragma unroll
      for (int r = 0; r < 4; r++){
        float h = fmaxf(v[r] + bias, 0.0f);
        Hs[(rbase + r)*HSTR + col] = (short)f2bf(h);
      }
    }
  }
  __syncthreads();
  // epilogue stage B: Gp[panel] partial = Hs @ Wt2[:, n0:n0+128]^T ; wave owns 32 rows
  f32x4 acc2[2][3] = {};
  for (int ks = 0; ks < 4; ks++){
    bf16x8 a2[2];
    #pragma unroll
    for (int i2 = 0; i2 < 2; i2++)
      a2[i2] = *(const bf16x8*)(Hs + (wid*32 + i2*16 + fr)*HSTR + ks*32 + q*8);
    #pragma unroll
    for (int j2 = 0; j2 < 3; j2++){
      bf16x8 b2 = *(const bf16x8*)(Wt2 + (size_t)(j2*16 + fr)*D_HID + n0 + ks*32 + q*8);
      #pragma unroll
      for (int i2 = 0; i2 < 2; i2++)
        acc2[i2][j2] = __builtin_amdgcn_mfma_f32_16x16x32_bf16(a2[i2], b2, acc2[i2][j2], 0, 0, 0);
    }
  }
  float* Gpp = Gp + (size_t)blockIdx.x*N_NODES*N_CLS;
  #pragma unroll
  for (int j2 = 0; j2 < 3; j2++){
    int col = j2*16 + fr;
    if (col < N_CLS){
      #pragma unroll
      for (int i2 = 0; i2 < 2; i2++){
        int rbase = m0 + wid*32 + i2*16 + q*4;
        f32x4 v = acc2[i2][j2];
        #pragma unroll
        for (int r = 0; r < 4; r++){
          int row = rbase + r;
          if (row < N_NODES)
            Gpp[(size_t)row*N_CLS + col] = v[r];   // plain store, no contention
        }
      }
    }
  }
}

// ---------------- reduce 16 panel partials -> G ----------------
__global__ void k_reduceG(const float* __restrict__ Gp, float* __restrict__ G){
  int idx = blockIdx.x*256 + threadIdx.x;
  if (idx < N_NODES*N_CLS){
    float s = 0.0f;
    #pragma unroll
    for (int p = 0; p < 16; p++)
      s += Gp[(size_t)p*N_NODES*N_CLS + idx];
    G[idx] = s;
  }
}

// ---------------- propagate(G) + b2 -> out ----------------
__global__ void k_gather2(const float* __restrict__ G, const int* __restrict__ csr_src,
                          const int* __restrict__ cursor, const int* __restrict__ deg,
                          const float* __restrict__ dinv, const float* __restrict__ b2,
                          float* __restrict__ out){
  __shared__ int   ssrc[64];
  __shared__ float scoef[64];
  const int i = blockIdx.x;
  const int t = threadIdx.x;
  const float di = dinv[i];
  const int cnt = deg[i];
  const int start = cursor[i] - cnt;
  float acc = 0.0f;
  if (t < N_CLS) acc = di*di * G[i*N_CLS + t];
  for (int c0 = 0; c0 < cnt; c0 += 64){
    int m = cnt - c0; if (m > 64) m = 64;
    if (t < m){
      int s = csr_src[start + c0 + t];
      ssrc[t] = s; scoef[t] = dinv[s]*di;
    }
    __syncthreads();
    if (t < N_CLS)
      for (int j = 0; j < m; j++)
        acc += scoef[j] * G[ssrc[j]*N_CLS + t];
    __syncthreads();
  }
  if (t < N_CLS) out[i*N_CLS + t] = acc + b2[t];
}

extern "C" void kernel_launch(void* const* d_in, const int* in_sizes, int n_in,
                              void* d_out, int out_size, void* d_ws, size_t ws_size,
                              hipStream_t stream){
  const float* x  = (const float*)d_in[0];
  const int*   ei = (const int*)d_in[1];
  const float* W1 = (const float*)d_in[2];
  const float* b1 = (const float*)d_in[3];
  const float* W2 = (const float*)d_in[4];
  const float* b2 = (const float*)d_in[5];
  float* out = (float*)d_out;

  char* ws = (char*)d_ws;
  size_t off = 0;
  auto alloc = [&](size_t bytes) -> void* {
    void* p = ws + off; off += (bytes + 255) & ~(size_t)255; return p;
  };
  int*   deg     = (int*)alloc((size_t)N_NODES*4);
  float* dinv    = (float*)alloc((size_t)N_NODES*4);
  int*   cursor  = (int*)alloc((size_t)N_NODES*4);
  int*   csr     = (int*)alloc((size_t)N_EDGES*4);
  unsigned short* Xb  = (unsigned short*)alloc((size_t)N_NODES*D_IN*2);
  unsigned short* Pb  = (unsigned short*)alloc((size_t)MP2*D_IN*2);
  unsigned short* Wt1 = (unsigned short*)alloc((size_t)D_HID*D_IN*2);
  unsigned short* Wt2 = (unsigned short*)alloc((size_t)48*D_HID*2);
  float* G  = (float*)alloc((size_t)N_NODES*N_CLS*4);
  float* Gp = (float*)alloc((size_t)16*N_NODES*N_CLS*4);   // 25.6 MB partials

  hipMemsetAsync(deg, 0, (size_t)N_NODES*4, stream);

  k_prep0<<<2500 + 1250, 256, 0, stream>>>(x, Xb, ei, deg);
  k_scan<<<1, 1024, 0, stream>>>(deg, cursor, dinv);
  k_fill<<<(N_EDGES+255)/256, 256, 0, stream>>>(ei, cursor, csr);
  k_gjoint<<<NGB + 1024 + 384, 256, 0, stream>>>(Xb, csr, cursor, deg, dinv, Pb,
                                                 W1, Wt1, W2, Wt2);
  k_gemm1f<<<dim3(D_HID/128, MP2/256), 512, 0, stream>>>(Pb, Wt1, b1, Wt2, Gp);
  k_reduceG<<<(N_NODES*N_CLS + 255)/256, 256, 0, stream>>>(Gp, G);
  k_gather2<<<N_NODES, 64, 0, stream>>>(G, csr, cursor, deg, dinv, b2, out);
}